// Round 2
// baseline (416.206 us; speedup 1.0000x reference)
//
#include <hip/hip_runtime.h>
#include <cmath>

// Decoder: 3-layer GRU (B=16, H=2048, E=128) + vocab projection (V=32000) + log_softmax.
// Memory-bound: 516 MB of weights streamed once. Roofline ~82us @ 6.8 TB/s.
// Strategy: barrier-free GEMV kernels. W streamed at 1KB-unique per instruction
// (lane = kk(16) x rowgroup(4): 4 distinct W rows per load), x/h read from L2
// (<=128 KB, produced by previous kernel). No LDS, no __syncthreads -> waves
// stall only on their own vmcnt, ~17 loads in flight each, 12-16 waves/CU.

#define BB 16
#define HH 2048
#define EE 128
#define VV 32000

__device__ __forceinline__ void fma4(float& a, const float4 w, const float4 x) {
  a = fmaf(w.x, x.x, a); a = fmaf(w.y, x.y, a);
  a = fmaf(w.z, x.z, a); a = fmaf(w.w, x.w, a);
}

// static-index select of a[i] from a 16-element register array (15 cndmask)
__device__ __forceinline__ float sel16(const float a[16], int i) {
  float s0 = (i & 1) ? a[1]  : a[0];
  float s1 = (i & 1) ? a[3]  : a[2];
  float s2 = (i & 1) ? a[5]  : a[4];
  float s3 = (i & 1) ? a[7]  : a[6];
  float s4 = (i & 1) ? a[9]  : a[8];
  float s5 = (i & 1) ? a[11] : a[10];
  float s6 = (i & 1) ? a[13] : a[12];
  float s7 = (i & 1) ? a[15] : a[14];
  float t0 = (i & 2) ? s1 : s0;
  float t1 = (i & 2) ? s3 : s2;
  float t2 = (i & 2) ? s5 : s4;
  float t3 = (i & 2) ? s7 : s6;
  float u0 = (i & 4) ? t1 : t0;
  float u1 = (i & 4) ? t3 : t2;
  return (i & 8) ? u1 : u0;
}

// GRU gate GEMV: rows [0,3H) -> gi = x @ W_ih.T ; rows [3H,6H) -> gh = h @ W_hh.T.
// Wave handles 4 rows (one per rg group) x all 16 batches.
// Lane (kk,rg): row = wid*4+rg, accumulates k-slice kk*4 + it*64.
// grid = 12288 rows / 4 rows/wave / 4 waves/block = 768 blocks.
template<int DIMI, bool EMB>
__global__ __launch_bounds__(256, 4)
void gru_gemv(const float* __restrict__ xsrc,   // EMB ? emb(V,E) : x(B,DIMI)
              const int* __restrict__ tokens,
              const float* __restrict__ hprev,  // (B,H)
              const float* __restrict__ Wih,    // (3H, DIMI)
              const float* __restrict__ Whh,    // (3H, H)
              float* __restrict__ gi,           // (B, 3H)
              float* __restrict__ gh)           // (B, 3H)
{
  const int tid  = threadIdx.x;
  const int lane = tid & 63;
  const int kk   = lane & 15;
  const int rg   = lane >> 4;
  const int wid  = blockIdx.x * 4 + (tid >> 6);
  const int row  = wid * 4 + rg;          // [0, 6H)
  const bool ih  = row < 3 * HH;          // wave-uniform (wid*4 straddles nothing)

  float acc[16] = {};

  if (ih) {
    const float* W = Wih + (size_t)row * DIMI;
    for (int it = 0; it < DIMI / 64; ++it) {
      const int k = it * 64 + kk * 4;
      const float4 wv = *(const float4*)(W + k);
      #pragma unroll
      for (int b = 0; b < 16; ++b) {
        float4 xv;
        if (EMB) {
          xv = *(const float4*)(xsrc + (size_t)tokens[b] * DIMI + k);
          xv.x = fmaxf(xv.x, 0.f); xv.y = fmaxf(xv.y, 0.f);
          xv.z = fmaxf(xv.z, 0.f); xv.w = fmaxf(xv.w, 0.f);
        } else {
          xv = *(const float4*)(xsrc + (size_t)b * DIMI + k);
        }
        fma4(acc[b], wv, xv);
      }
    }
  } else {
    const float* W = Whh + (size_t)(row - 3 * HH) * HH;
    for (int it = 0; it < HH / 64; ++it) {
      const int k = it * 64 + kk * 4;
      const float4 wv = *(const float4*)(W + k);
      #pragma unroll
      for (int b = 0; b < 16; ++b) {
        const float4 xv = *(const float4*)(hprev + (size_t)b * HH + k);
        fma4(acc[b], wv, xv);
      }
    }
  }

  // reduce over the 16 kk-lanes (masks 1,2,4,8 stay inside the rg group)
  #pragma unroll
  for (int b = 0; b < 16; ++b) {
    float a = acc[b];
    a += __shfl_xor(a, 1, 64);
    a += __shfl_xor(a, 2, 64);
    a += __shfl_xor(a, 4, 64);
    a += __shfl_xor(a, 8, 64);
    acc[b] = a;
  }

  // every lane writes one output: batch = kk, its rg's row
  const float v = sel16(acc, kk);
  float* dst = ih ? gi : gh;
  const int col = ih ? row : row - 3 * HH;
  dst[(size_t)kk * (3 * HH) + col] = v;
}

// Elementwise GRU gate math: h' = (1-z)*n + z*h. 32768 threads.
__global__ __launch_bounds__(256)
void gru_epi(const float* __restrict__ gi, const float* __restrict__ gh,
             const float* __restrict__ bih, const float* __restrict__ bhh,
             const float* __restrict__ hprev, float* __restrict__ hout)
{
  const int idx = blockIdx.x * 256 + threadIdx.x;  // B*H
  const int j = idx & (HH - 1);
  const size_t base = (size_t)(idx >> 11) * (3 * HH);
  const float ir = gi[base + j]           + bih[j];
  const float iz = gi[base + HH + j]      + bih[HH + j];
  const float in_ = gi[base + 2 * HH + j] + bih[2 * HH + j];
  const float hr = gh[base + j]           + bhh[j];
  const float hz = gh[base + HH + j]      + bhh[HH + j];
  const float hn = gh[base + 2 * HH + j]  + bhh[2 * HH + j];
  const float r = 1.f / (1.f + expf(-(ir + hr)));
  const float z = 1.f / (1.f + expf(-(iz + hz)));
  const float n = tanhf(in_ + r * hn);
  hout[idx] = (1.f - z) * n + z * hprev[idx];
}

// Vocab projection: wave handles 8 rows (2 per rg group) x 16 batches.
// grid = 32000 / 8 / 4 = 1000 blocks.
__global__ __launch_bounds__(256, 4)
void out_kernel(const float* __restrict__ h2, const float* __restrict__ Wout,
                const float* __restrict__ bout, float* __restrict__ logits)
{
  const int tid  = threadIdx.x;
  const int lane = tid & 63;
  const int kk   = lane & 15;
  const int rg   = lane >> 4;
  const int wid  = blockIdx.x * 4 + (tid >> 6);
  const int row0 = wid * 8 + rg * 2;      // lane's rows: row0, row0+1

  float a0[16] = {};
  float a1[16] = {};
  const float* W0 = Wout + (size_t)row0 * HH;
  const float* W1 = W0 + HH;

  for (int it = 0; it < HH / 64; ++it) {
    const int k = it * 64 + kk * 4;
    const float4 w0 = *(const float4*)(W0 + k);
    const float4 w1 = *(const float4*)(W1 + k);
    #pragma unroll
    for (int b = 0; b < 16; ++b) {
      const float4 xv = *(const float4*)(h2 + (size_t)b * HH + k);
      fma4(a0[b], w0, xv);
      fma4(a1[b], w1, xv);
    }
  }

  #pragma unroll
  for (int b = 0; b < 16; ++b) {
    float x0 = a0[b], x1 = a1[b];
    x0 += __shfl_xor(x0, 1, 64); x1 += __shfl_xor(x1, 1, 64);
    x0 += __shfl_xor(x0, 2, 64); x1 += __shfl_xor(x1, 2, 64);
    x0 += __shfl_xor(x0, 4, 64); x1 += __shfl_xor(x1, 4, 64);
    x0 += __shfl_xor(x0, 8, 64); x1 += __shfl_xor(x1, 8, 64);
    a0[b] = x0; a1[b] = x1;
  }

  const float v0 = sel16(a0, kk) + bout[row0];
  const float v1 = sel16(a1, kk) + bout[row0 + 1];
  float2 o; o.x = v0; o.y = v1;
  *(float2*)(logits + (size_t)kk * VV + row0) = o;   // lane writes batch kk
}

// In-place log_softmax over each row of logits (16 rows x 32000).
__global__ __launch_bounds__(1024)
void lsm_kernel(float* __restrict__ logp)
{
  const int b   = blockIdx.x;
  const int tid = threadIdx.x;
  float* row = logp + (size_t)b * VV;
  const float4* r4 = (const float4*)row;
  __shared__ float red[16];
  const int wv = tid >> 6, ln = tid & 63;

  float m = -3.4e38f;
  for (int i = tid; i < VV / 4; i += 1024) {
    float4 v = r4[i];
    m = fmaxf(m, fmaxf(fmaxf(v.x, v.y), fmaxf(v.z, v.w)));
  }
  #pragma unroll
  for (int s = 1; s < 64; s <<= 1) m = fmaxf(m, __shfl_xor(m, s, 64));
  if (ln == 0) red[wv] = m;
  __syncthreads();
  if (tid == 0) {
    float mm = red[0];
    for (int w = 1; w < 16; ++w) mm = fmaxf(mm, red[w]);
    red[0] = mm;
  }
  __syncthreads();
  const float M = red[0];
  __syncthreads();

  float s = 0.f;
  for (int i = tid; i < VV / 4; i += 1024) {
    float4 v = r4[i];
    s += expf(v.x - M) + expf(v.y - M) + expf(v.z - M) + expf(v.w - M);
  }
  #pragma unroll
  for (int t = 1; t < 64; t <<= 1) s += __shfl_xor(s, t, 64);
  if (ln == 0) red[wv] = s;
  __syncthreads();
  if (tid == 0) {
    float ss = 0.f;
    for (int w = 0; w < 16; ++w) ss += red[w];
    red[0] = M + logf(ss);
  }
  __syncthreads();
  const float L = red[0];

  float4* w4 = (float4*)row;
  for (int i = tid; i < VV / 4; i += 1024) {
    float4 v = r4[i];
    v.x -= L; v.y -= L; v.z -= L; v.w -= L;
    w4[i] = v;
  }
}

extern "C" void kernel_launch(void* const* d_in, const int* in_sizes, int n_in,
                              void* d_out, int out_size, void* d_ws, size_t ws_size,
                              hipStream_t stream)
{
  const int*   tokens = (const int*)d_in[0];
  const float* hidden = (const float*)d_in[1]; // (3,B,H)
  const float* emb    = (const float*)d_in[2]; // (V,E)
  const float* Wih0 = (const float*)d_in[3];
  const float* Whh0 = (const float*)d_in[4];
  const float* bih0 = (const float*)d_in[5];
  const float* bhh0 = (const float*)d_in[6];
  const float* Wih1 = (const float*)d_in[7];
  const float* Whh1 = (const float*)d_in[8];
  const float* bih1 = (const float*)d_in[9];
  const float* bhh1 = (const float*)d_in[10];
  const float* Wih2 = (const float*)d_in[11];
  const float* Whh2 = (const float*)d_in[12];
  const float* bih2 = (const float*)d_in[13];
  const float* bhh2 = (const float*)d_in[14];
  const float* Wout = (const float*)d_in[15];
  const float* bout = (const float*)d_in[16];

  float* outp = (float*)d_out;
  float* logp = outp;                       // (B,V)
  float* hnew = outp + (size_t)BB * VV;     // (3,B,H)
  float* h0 = hnew;
  float* h1 = hnew + BB * HH;
  float* h2 = hnew + 2 * BB * HH;

  float* gi = (float*)d_ws;                 // (B, 3H)
  float* gh = gi + (size_t)BB * 3 * HH;     // (B, 3H)

  gru_gemv<EE, true ><<<768, 256, 0, stream>>>(emb, tokens, hidden, Wih0, Whh0, gi, gh);
  gru_epi<<<128, 256, 0, stream>>>(gi, gh, bih0, bhh0, hidden, h0);
  gru_gemv<HH, false><<<768, 256, 0, stream>>>(h0, nullptr, hidden + BB * HH, Wih1, Whh1, gi, gh);
  gru_epi<<<128, 256, 0, stream>>>(gi, gh, bih1, bhh1, hidden + BB * HH, h1);
  gru_gemv<HH, false><<<768, 256, 0, stream>>>(h1, nullptr, hidden + 2 * BB * HH, Wih2, Whh2, gi, gh);
  gru_epi<<<128, 256, 0, stream>>>(gi, gh, bih2, bhh2, hidden + 2 * BB * HH, h2);
  out_kernel<<<1000, 256, 0, stream>>>(h2, Wout, bout, logp);
  lsm_kernel<<<16, 1024, 0, stream>>>(logp);
}

// Round 3
// 263.694 us; speedup vs baseline: 1.5784x; 1.5784x over previous
//
#include <hip/hip_runtime.h>
#include <cmath>

// Decoder: 3-layer GRU (B=16, H=2048, E=128) + vocab projection (V=32000) + log_softmax.
// Memory-bound: 516 MB of fp32 weights streamed once. Roofline ~82us @ ~6.8 TB/s.
//
// Structure: per block, stage the (B x DIM) activation into LDS ONCE (128 KB,
// one barrier), then stream W barrier-free. Lane = kk(16) x rg(4): every
// global_load_dwordx4 covers 4 distinct W rows x 64B = 1KB unique. x-reads are
// ds_read_b128 with 4-way same-address broadcast (free) + 2-way bank alias
// (free). VALU floor is ~31% (B=16 -> 16 FMA per W element, 128 FMA/cyc/CU).

#define BB 16
#define HH 2048
#define EE 128
#define VV 32000

__device__ __forceinline__ void fma4(float& a, const float4 w, const float4 x) {
  a = fmaf(w.x, x.x, a); a = fmaf(w.y, x.y, a);
  a = fmaf(w.z, x.z, a); a = fmaf(w.w, x.w, a);
}

// static-index select of a[i] (15 cndmask; avoids runtime-indexed reg array)
__device__ __forceinline__ float sel16(const float a[16], int i) {
  float s0 = (i & 1) ? a[1]  : a[0];
  float s1 = (i & 1) ? a[3]  : a[2];
  float s2 = (i & 1) ? a[5]  : a[4];
  float s3 = (i & 1) ? a[7]  : a[6];
  float s4 = (i & 1) ? a[9]  : a[8];
  float s5 = (i & 1) ? a[11] : a[10];
  float s6 = (i & 1) ? a[13] : a[12];
  float s7 = (i & 1) ? a[15] : a[14];
  float t0 = (i & 2) ? s1 : s0;
  float t1 = (i & 2) ? s3 : s2;
  float t2 = (i & 2) ? s5 : s4;
  float t3 = (i & 2) ? s7 : s6;
  float u0 = (i & 4) ? t1 : t0;
  float u1 = (i & 4) ? t3 : t2;
  return (i & 8) ? u1 : u0;
}

// stage (BB x DIM) fp32 into LDS, coalesced float4; EMB: rows are relu(emb[tok[b]])
template<int DIM, bool EMB>
__device__ __forceinline__
void stage(float* sx, const float* __restrict__ src, const int* __restrict__ tokens, int tid) {
  constexpr int F4 = DIM / 4;
  for (int f = tid; f < BB * F4; f += 512) {
    const int b = f / F4;
    const int i = (f % F4) * 4;
    float4 v;
    if (EMB) {
      v = *(const float4*)(src + (size_t)tokens[b] * DIM + i);
      v.x = fmaxf(v.x, 0.f); v.y = fmaxf(v.y, 0.f);
      v.z = fmaxf(v.z, 0.f); v.w = fmaxf(v.w, 0.f);
    } else {
      v = *(const float4*)(src + (size_t)b * DIM + i);
    }
    *(float4*)(sx + b * DIM + i) = v;
  }
}

// one 4-row unit: this lane's row = unit*4 + rg, k-slices kk*4 (+it*64).
// returns the reduced dot for (batch kk, row rg's row).
template<int DIM>
__device__ __forceinline__
float unit_gemv(const float* sx, const float* __restrict__ W, int row, int kk) {
  float acc[16] = {};
  const float* Wr = W + (size_t)row * DIM;
  #pragma unroll 2
  for (int it = 0; it < DIM / 64; ++it) {
    const int k = it * 64 + kk * 4;
    const float4 w4 = *(const float4*)(Wr + k);
    #pragma unroll
    for (int b = 0; b < 16; ++b) {
      const float4 xv = *(const float4*)(sx + b * DIM + k);
      fma4(acc[b], w4, xv);
    }
  }
  #pragma unroll
  for (int b = 0; b < 16; ++b) {
    float a = acc[b];
    a += __shfl_xor(a, 1, 64);
    a += __shfl_xor(a, 2, 64);
    a += __shfl_xor(a, 4, 64);
    a += __shfl_xor(a, 8, 64);
    acc[b] = a;
  }
  return sel16(acc, kk);
}

// GRU gate GEMV. Blocks [0,nbih): gi = x @ W_ih.T ; blocks [nbih,grid): gh = h @ W_hh.T.
// 512 threads = 8 waves; each wave grid-strides over 4-row units.
template<int DIMI, bool EMB>
__global__ __launch_bounds__(512, 1)
void gru_gemv(const float* __restrict__ xsrc,   // EMB ? emb(V,E) : x(B,DIMI)
              const int* __restrict__ tokens,
              const float* __restrict__ hprev,  // (B,H)
              const float* __restrict__ Wih,    // (3H, DIMI)
              const float* __restrict__ Whh,    // (3H, H)
              float* __restrict__ gi,           // (B,3H)
              float* __restrict__ gh,           // (B,3H)
              int nbih)
{
  __shared__ float sx[BB * HH];   // 128 KB
  const int tid  = threadIdx.x;
  const int lane = tid & 63;
  const int kk   = lane & 15;
  const int rg   = lane >> 4;
  const int wv   = tid >> 6;
  const int bx   = blockIdx.x;
  constexpr int NU = 3 * HH / 4;  // 4-row units per matrix

  if (bx < nbih) {
    stage<DIMI, EMB>(sx, xsrc, tokens, tid);
    __syncthreads();
    const int nw = nbih * 8;
    for (int u = bx * 8 + wv; u < NU; u += nw) {
      const int row = u * 4 + rg;
      gi[(size_t)kk * (3 * HH) + row] = unit_gemv<DIMI>(sx, Wih, row, kk);
    }
  } else {
    stage<HH, false>(sx, hprev, nullptr, tid);
    __syncthreads();
    const int nw = (gridDim.x - nbih) * 8;
    for (int u = (bx - nbih) * 8 + wv; u < NU; u += nw) {
      const int row = u * 4 + rg;
      gh[(size_t)kk * (3 * HH) + row] = unit_gemv<HH>(sx, Whh, row, kk);
    }
  }
}

// Elementwise GRU gate math: h' = (1-z)*n + z*h. B*H threads.
__global__ __launch_bounds__(256)
void gru_epi(const float* __restrict__ gi, const float* __restrict__ gh,
             const float* __restrict__ bih, const float* __restrict__ bhh,
             const float* __restrict__ hprev, float* __restrict__ hout)
{
  const int idx = blockIdx.x * 256 + threadIdx.x;
  const int j = idx & (HH - 1);
  const size_t base = (size_t)(idx >> 11) * (3 * HH);
  const float ir  = gi[base + j]          + bih[j];
  const float iz  = gi[base + HH + j]     + bih[HH + j];
  const float in_ = gi[base + 2 * HH + j] + bih[2 * HH + j];
  const float hr  = gh[base + j]          + bhh[j];
  const float hz  = gh[base + HH + j]     + bhh[HH + j];
  const float hn  = gh[base + 2 * HH + j] + bhh[2 * HH + j];
  const float r = 1.f / (1.f + expf(-(ir + hr)));
  const float z = 1.f / (1.f + expf(-(iz + hz)));
  const float n = tanhf(in_ + r * hn);
  hout[idx] = (1.f - z) * n + z * hprev[idx];
}

// Vocab projection: same structure, all blocks stage h2.
__global__ __launch_bounds__(512, 1)
void out_kernel(const float* __restrict__ h2, const float* __restrict__ Wout,
                const float* __restrict__ bout, float* __restrict__ logits)
{
  __shared__ float sx[BB * HH];
  const int tid  = threadIdx.x;
  const int lane = tid & 63;
  const int kk   = lane & 15;
  const int rg   = lane >> 4;
  const int wv   = tid >> 6;

  stage<HH, false>(sx, h2, nullptr, tid);
  __syncthreads();

  const int nw = gridDim.x * 8;
  for (int u = blockIdx.x * 8 + wv; u < VV / 4; u += nw) {
    const int row = u * 4 + rg;
    const float v = unit_gemv<HH>(sx, Wout, row, kk);
    logits[(size_t)kk * VV + row] = v + bout[row];
  }
}

// In-place log_softmax over each row of logits (16 rows x 32000).
__global__ __launch_bounds__(1024)
void lsm_kernel(float* __restrict__ logp)
{
  const int b   = blockIdx.x;
  const int tid = threadIdx.x;
  float* row = logp + (size_t)b * VV;
  const float4* r4 = (const float4*)row;
  __shared__ float red[16];
  const int wv = tid >> 6, ln = tid & 63;

  float m = -3.4e38f;
  for (int i = tid; i < VV / 4; i += 1024) {
    float4 v = r4[i];
    m = fmaxf(m, fmaxf(fmaxf(v.x, v.y), fmaxf(v.z, v.w)));
  }
  #pragma unroll
  for (int s = 1; s < 64; s <<= 1) m = fmaxf(m, __shfl_xor(m, s, 64));
  if (ln == 0) red[wv] = m;
  __syncthreads();
  if (tid == 0) {
    float mm = red[0];
    for (int w = 1; w < 16; ++w) mm = fmaxf(mm, red[w]);
    red[0] = mm;
  }
  __syncthreads();
  const float M = red[0];
  __syncthreads();

  float s = 0.f;
  for (int i = tid; i < VV / 4; i += 1024) {
    float4 v = r4[i];
    s += expf(v.x - M) + expf(v.y - M) + expf(v.z - M) + expf(v.w - M);
  }
  #pragma unroll
  for (int t = 1; t < 64; t <<= 1) s += __shfl_xor(s, t, 64);
  if (ln == 0) red[wv] = s;
  __syncthreads();
  if (tid == 0) {
    float ss = 0.f;
    for (int w = 0; w < 16; ++w) ss += red[w];
    red[0] = M + logf(ss);
  }
  __syncthreads();
  const float L = red[0];

  float4* w4 = (float4*)row;
  for (int i = tid; i < VV / 4; i += 1024) {
    float4 v = r4[i];
    v.x -= L; v.y -= L; v.z -= L; v.w -= L;
    w4[i] = v;
  }
}

extern "C" void kernel_launch(void* const* d_in, const int* in_sizes, int n_in,
                              void* d_out, int out_size, void* d_ws, size_t ws_size,
                              hipStream_t stream)
{
  const int*   tokens = (const int*)d_in[0];
  const float* hidden = (const float*)d_in[1]; // (3,B,H)
  const float* emb    = (const float*)d_in[2]; // (V,E)
  const float* Wih0 = (const float*)d_in[3];
  const float* Whh0 = (const float*)d_in[4];
  const float* bih0 = (const float*)d_in[5];
  const float* bhh0 = (const float*)d_in[6];
  const float* Wih1 = (const float*)d_in[7];
  const float* Whh1 = (const float*)d_in[8];
  const float* bih1 = (const float*)d_in[9];
  const float* bhh1 = (const float*)d_in[10];
  const float* Wih2 = (const float*)d_in[11];
  const float* Whh2 = (const float*)d_in[12];
  const float* bih2 = (const float*)d_in[13];
  const float* bhh2 = (const float*)d_in[14];
  const float* Wout = (const float*)d_in[15];
  const float* bout = (const float*)d_in[16];

  float* outp = (float*)d_out;
  float* logp = outp;                       // (B,V)
  float* hnew = outp + (size_t)BB * VV;     // (3,B,H)
  float* h0 = hnew;
  float* h1 = hnew + BB * HH;
  float* h2 = hnew + 2 * BB * HH;

  float* gi = (float*)d_ws;                 // (B,3H)
  float* gh = gi + (size_t)BB * 3 * HH;     // (B,3H)

  // layer 0: W_ih0 is 3MB (DIM=128) -> 64 ih blocks; 192 hh blocks = 192 hh tiles
  gru_gemv<EE, true ><<<256, 512, 0, stream>>>(emb, tokens, hidden, Wih0, Whh0, gi, gh, 64);
  gru_epi<<<128, 256, 0, stream>>>(gi, gh, bih0, bhh0, hidden, h0);
  gru_gemv<HH, false><<<256, 512, 0, stream>>>(h0, nullptr, hidden + BB * HH, Wih1, Whh1, gi, gh, 128);
  gru_epi<<<128, 256, 0, stream>>>(gi, gh, bih1, bhh1, hidden + BB * HH, h1);
  gru_gemv<HH, false><<<256, 512, 0, stream>>>(h1, nullptr, hidden + 2 * BB * HH, Wih2, Whh2, gi, gh, 128);
  gru_epi<<<128, 256, 0, stream>>>(gi, gh, bih2, bhh2, hidden + 2 * BB * HH, h2);
  out_kernel<<<256, 512, 0, stream>>>(h2, Wout, bout, logp);
  lsm_kernel<<<16, 1024, 0, stream>>>(logp);
}